// Round 10
// baseline (208.324 us; speedup 1.0000x reference)
//
#include <hip/hip_runtime.h>
#include <stdint.h>

#define NB 4096   // query rows
#define NM 8192   // memory rows
#define ND 1024   // feature dim

typedef __attribute__((ext_vector_type(8))) short bf16x8;
typedef __attribute__((ext_vector_type(4))) float f32x4;
typedef __attribute__((ext_vector_type(8))) unsigned short u16x8;

static __device__ __forceinline__ unsigned short f2bf(float f) {
  union { float f; uint32_t u; } v; v.f = f;
  uint32_t u = v.u;
  u += 0x7fffu + ((u >> 16) & 1u);   // RNE
  return (unsigned short)(u >> 16);
}
static __device__ __forceinline__ float bf2f(unsigned short b) {
  union { uint32_t u; float f; } v; v.u = ((uint32_t)b) << 16; return v.f;
}

static __device__ __forceinline__ void gload_lds16(const void* g, void* l) {
  __builtin_amdgcn_global_load_lds(
      (__attribute__((address_space(1))) void*)g,
      (__attribute__((address_space(3))) void*)l, 16, 0, 0);
}

#define BAR()   __builtin_amdgcn_s_barrier()
#define LGKM0() asm volatile("s_waitcnt lgkmcnt(0)" ::: "memory")
#define VMC8()  asm volatile("s_waitcnt vmcnt(8)" ::: "memory")
#define VMC2()  asm volatile("s_waitcnt vmcnt(2)" ::: "memory")
#define VMC0()  asm volatile("s_waitcnt vmcnt(0)" ::: "memory")

// ---- L2-normalize rows of x [rows x 1024] fp32 -> bf16 out -----------------
__global__ void nrm_kernel(const float* __restrict__ x, unsigned short* __restrict__ out) {
  const int row = blockIdx.x, t = threadIdx.x;
  const float4 v = ((const float4*)(x + (size_t)row * ND))[t];
  float ss = v.x * v.x + v.y * v.y + v.z * v.z + v.w * v.w;
  #pragma unroll
  for (int o = 32; o > 0; o >>= 1) ss += __shfl_xor(ss, o);
  __shared__ float red[4];
  if ((t & 63) == 0) red[t >> 6] = ss;
  __syncthreads();
  ss = (red[0] + red[1]) + (red[2] + red[3]);
  const float sc = 1.0f / fmaxf(sqrtf(ss), 1e-12f);
  ushort4 o4;
  o4.x = f2bf(v.x * sc); o4.y = f2bf(v.y * sc);
  o4.z = f2bf(v.z * sc); o4.w = f2bf(v.w * sc);
  ((ushort4*)(out + (size_t)row * ND))[t] = o4;
}

// ---- transpose memn [8192x1024] bf16 -> memt [1024x8192] bf16 --------------
__global__ void tr_kernel(const unsigned short* __restrict__ memn, unsigned short* __restrict__ memt) {
  __shared__ unsigned short Ts[64][66];
  const int t = threadIdx.x;
  const int d0 = blockIdx.x * 64, m0 = blockIdx.y * 64;
  #pragma unroll
  for (int r = 0; r < 2; ++r) {
    const int lrow = r * 32 + (t >> 3);
    const int lcol = (t & 7) * 8;
    u16x8 v = *(const u16x8*)(memn + (size_t)(m0 + lrow) * ND + d0 + lcol);
    #pragma unroll
    for (int j = 0; j < 8; ++j) Ts[lcol + j][lrow] = v[j];
  }
  __syncthreads();
  #pragma unroll
  for (int r = 0; r < 2; ++r) {
    const int orow = r * 32 + (t >> 3);
    const int ocol = (t & 7) * 8;
    u16x8 o;
    #pragma unroll
    for (int j = 0; j < 8; ++j) o[j] = Ts[orow][ocol + j];
    *(u16x8*)(memt + (size_t)(d0 + orow) * NM + m0 + ocol) = o;
  }
}

// ============ 256x256 GEMM, 4-phase ring schedule (WAR-distance fix) ========
// C[M,N] = A[M,K] * B[N,K]^T (both bf16 row-major, ld = K stride).
// 512 thr = 8 waves (2M x 4N), per-wave 128x64 out, BK=64, dbuf LDS 128 KiB.
// Swizzle: phys_cb = cb ^ ((row&7)<<4) on stage-source + ds_read (0 conflicts).
// Fragment rows: A row = m*32 + wr*16 + lr; B row = nf*64 + wc*16 + lr
// (alo=A-h0, ahi=A-h1, blo=B-h0, bhi=B-h1 for every wave).
// r10 WAR fix: every ds_read batch is issued right AFTER an MFMA cluster and
// targets registers whose last MFMA consumer was >=1 full cluster (+barrier)
// earlier, so the read's VGPR write never collides with in-flight MFMA
// operand reads (the r6-r9 serializer). blo is ping-ponged (bloA/bloB).
//   P1: Q1=MFMA(alo,blo)->acc[0:4][0:2];  read bhi(T);              BAR
//   P2: Q2=MFMA(alo,bhi)->acc[0:4][2:4];  read ahi(T);  stage Blo(T+2); VMC2; BAR
//   P3: Q3=MFMA(ahi,bhi)->acc[4:8][2:4];  read blo'(T+1); stage Bhi,Alo(T+2); BAR
//   P4: Q4=MFMA(ahi,blo)->acc[4:8][0:2];  read alo(T+1); stage Ahi(T+2); BAR
// Region liveness (stage T+2 into buf p while T still read): B-lo free after
// P1 (blo(T) read P4(T-1), block-wide by P1 BAR), B-hi after P2, A-lo after
// P2 (alo read P4(T-1), BAR'd P1; staged P3), A-hi after P3. All >=1 BAR. ✓
// vmcnt(2) at P2 drains tile T+1's 8 stages (issued tile T-1), leaves Blo(T+2).
// MODE 0: fp32 C partials (split-K).  MODE 1: E=exp(C) bf16 + psum row-sums.
template<int MODE>
__global__ __launch_bounds__(512, 2) void gemm4r(
    const unsigned short* __restrict__ A, const unsigned short* __restrict__ B,
    void* __restrict__ Cv, float* __restrict__ psum,
    int ld, int ldc, int mt, int tps, int kchunk, unsigned long long cstride)
{
  extern __shared__ char smem[];   // [buf][A 32K | B 32K] x2 = 128 KiB
  const int t = threadIdx.x;
  const int w = t >> 6, l = t & 63;
  const int wr = w >> 2, wc = w & 3;
  const int nwg = gridDim.x, cpx = nwg >> 3;
  const int id = (blockIdx.x & 7) * cpx + (blockIdx.x >> 3);  // XCD swizzle
  const int ksp = id / tps, rem = id % tps;
  const int brow = rem % mt, bcol = rem / mt;
  const int k0 = ksp * kchunk;
  const int nt = kchunk >> 6;          // K-tiles (even)

  const int srow = l >> 3;                       // staging row-in-8-group
  const int scol = ((l & 7) ^ srow) << 3;        // pre-swizzled global col
  const int lr = l & 15, lhi = l >> 4;
  const int swz = (l & 7) << 4;
  const int cbk0 = (lhi * 16) ^ swz;
  const int cbk1 = (64 + lhi * 16) ^ swz;
  const int aoffr = (wr * 16 + lr) * 128;        // + m*4096
  const int boffr = (wc * 16 + lr) * 128;        // + nf*8192

  const unsigned short* Ab = A + (size_t)(brow * 256 + w * 8 + srow) * ld + k0 + scol;
  const unsigned short* Bb = B + (size_t)(bcol * 256 + w * 8 + srow) * ld + k0 + scol;

  auto stageA = [&](int p, int h, int tau) {     // one region = 2 gloads/wave
    const int kt = (tau < nt ? tau : nt - 1) << 6;
    const unsigned short* g = Ab + (size_t)(h * 128) * ld + kt;
    char* d = smem + p * 65536 + h * 16384 + w * 1024;
    gload_lds16(g, d);
    gload_lds16(g + (size_t)64 * ld, d + 8192);
  };
  auto stageB = [&](int p, int h, int tau) {
    const int kt = (tau < nt ? tau : nt - 1) << 6;
    const unsigned short* g = Bb + (size_t)(h * 128) * ld + kt;
    char* d = smem + p * 65536 + 32768 + h * 16384 + w * 1024;
    gload_lds16(g, d);
    gload_lds16(g + (size_t)64 * ld, d + 8192);
  };
  auto ldA = [&](int p, int m, int kk) -> bf16x8 {   // A row m*32+wr*16+lr
    return *(const bf16x8*)(smem + p * 65536 + m * 4096 + aoffr + (kk ? cbk1 : cbk0));
  };
  auto ldB = [&](int p, int nf, int kk) -> bf16x8 {  // B row nf*64+wc*16+lr
    return *(const bf16x8*)(smem + p * 65536 + 32768 + nf * 8192 + boffr + (kk ? cbk1 : cbk0));
  };

  f32x4 acc[8][4] = {};
  bf16x8 alo[4][2], ahi[4][2], bloA[2][2], bloB[2][2], bhi[2][2];

  // prologue: stage tiles 0,1; drain tile0; prime alo(0), bloA(0).
  stageA(0, 0, 0); stageA(0, 1, 0); stageB(0, 0, 0); stageB(0, 1, 0);
  stageA(1, 0, 1); stageA(1, 1, 1); stageB(1, 0, 1); stageB(1, 1, 1);
  VMC8();
  BAR();
  #pragma unroll
  for (int m = 0; m < 4; ++m) { alo[m][0] = ldA(0, m, 0); alo[m][1] = ldA(0, m, 1); }
  #pragma unroll
  for (int n = 0; n < 2; ++n) { bloA[n][0] = ldB(0, n, 0); bloA[n][1] = ldB(0, n, 1); }

  #define CL(AF, BF, MO, NO)                                                   \
    __builtin_amdgcn_s_setprio(1);                                             \
    _Pragma("unroll")                                                          \
    for (int kk = 0; kk < 2; ++kk)                                             \
      _Pragma("unroll")                                                        \
      for (int m = 0; m < 4; ++m)                                              \
        _Pragma("unroll")                                                      \
        for (int n = 0; n < 2; ++n)                                            \
          acc[MO + m][NO + n] = __builtin_amdgcn_mfma_f32_16x16x32_bf16(       \
              AF[m][kk], BF[n][kk], acc[MO + m][NO + n], 0, 0, 0);             \
    __builtin_amdgcn_s_setprio(0);

  const int niter = nt >> 1;
  for (int i = 0; i < niter; ++i) {
    const int t2 = 2 * i + 2, t3 = 2 * i + 3;
    // ================= tile T = 2i (buf 0, blo = bloA) =================
    // P1
    LGKM0();
    CL(alo, bloA, 0, 0);
    #pragma unroll
    for (int n = 0; n < 2; ++n) { bhi[n][0] = ldB(0, 2 + n, 0); bhi[n][1] = ldB(0, 2 + n, 1); }
    BAR();
    // P2
    LGKM0();
    CL(alo, bhi, 0, 2);
    #pragma unroll
    for (int m = 0; m < 4; ++m) { ahi[m][0] = ldA(0, 4 + m, 0); ahi[m][1] = ldA(0, 4 + m, 1); }
    stageB(0, 0, t2);
    VMC2();
    BAR();
    // P3
    LGKM0();
    CL(ahi, bhi, 4, 2);
    #pragma unroll
    for (int n = 0; n < 2; ++n) { bloB[n][0] = ldB(1, n, 0); bloB[n][1] = ldB(1, n, 1); }
    stageB(0, 1, t2); stageA(0, 0, t2);
    BAR();
    // P4
    LGKM0();
    CL(ahi, bloA, 4, 0);
    #pragma unroll
    for (int m = 0; m < 4; ++m) { alo[m][0] = ldA(1, m, 0); alo[m][1] = ldA(1, m, 1); }
    stageA(0, 1, t2);
    BAR();
    // ================= tile T+1 (buf 1, blo = bloB) ====================
    // P1
    LGKM0();
    CL(alo, bloB, 0, 0);
    #pragma unroll
    for (int n = 0; n < 2; ++n) { bhi[n][0] = ldB(1, 2 + n, 0); bhi[n][1] = ldB(1, 2 + n, 1); }
    BAR();
    // P2
    LGKM0();
    CL(alo, bhi, 0, 2);
    #pragma unroll
    for (int m = 0; m < 4; ++m) { ahi[m][0] = ldA(1, 4 + m, 0); ahi[m][1] = ldA(1, 4 + m, 1); }
    stageB(1, 0, t3);
    VMC2();
    BAR();
    // P3
    LGKM0();
    CL(ahi, bhi, 4, 2);
    #pragma unroll
    for (int n = 0; n < 2; ++n) { bloA[n][0] = ldB(0, n, 0); bloA[n][1] = ldB(0, n, 1); }
    stageB(1, 1, t3); stageA(1, 0, t3);
    BAR();
    // P4
    LGKM0();
    CL(ahi, bloB, 4, 0);
    #pragma unroll
    for (int m = 0; m < 4; ++m) { alo[m][0] = ldA(0, m, 0); alo[m][1] = ldA(0, m, 1); }
    stageA(1, 1, t3);
    BAR();
  }
  #undef CL

  // epilogue: C row = brow*256 + m*32 + wr*16 + lhi*4 + j,
  //           C col = bcol*256 + n*64 + wc*16 + lr     [m89/m91 C/D map]
  const int crow0 = brow * 256 + wr * 16 + lhi * 4;
  const int ccol0 = bcol * 256 + wc * 16 + lr;
  if constexpr (MODE == 1) {
    // E = exp(sim) bf16 + per-block row-sum partials (deterministic)
    unsigned short* Cp = (unsigned short*)Cv;
    float rs[8][4];
    #pragma unroll
    for (int m = 0; m < 8; ++m)
      #pragma unroll
      for (int j = 0; j < 4; ++j) rs[m][j] = 0.f;
    #pragma unroll
    for (int m = 0; m < 8; ++m)
      #pragma unroll
      for (int n = 0; n < 4; ++n)
        #pragma unroll
        for (int j = 0; j < 4; ++j) {
          const float e = __expf(acc[m][n][j]);
          rs[m][j] += e;
          Cp[(size_t)(crow0 + m * 32 + j) * ldc + ccol0 + n * 64] = f2bf(e);
        }
    // 16-lane (lr) reduce -> lanes lr==0 hold this wave's 64-col sums
    #pragma unroll
    for (int m = 0; m < 8; ++m)
      #pragma unroll
      for (int j = 0; j < 4; ++j)
        #pragma unroll
        for (int o = 1; o < 16; o <<= 1) rs[m][j] += __shfl_xor(rs[m][j], o);
    VMC0();            // in-flight clamped stages still write smem
    __syncthreads();
    float* ls = (float*)smem;   // [wc][256 rows] = 4 KiB
    if (lr == 0) {
      #pragma unroll
      for (int m = 0; m < 8; ++m)
        #pragma unroll
        for (int j = 0; j < 4; ++j)
          ls[wc * 256 + wr * 16 + m * 32 + lhi * 4 + j] = rs[m][j];
    }
    __syncthreads();
    if (t < 256) {
      const float s4 = ls[t] + ls[256 + t] + ls[512 + t] + ls[768 + t];
      psum[(size_t)bcol * NB + brow * 256 + t] = s4;
    }
  } else {
    float* Cp = (float*)Cv + (unsigned long long)ksp * cstride;
    #pragma unroll
    for (int m = 0; m < 8; ++m)
      #pragma unroll
      for (int n = 0; n < 4; ++n)
        #pragma unroll
        for (int j = 0; j < 4; ++j)
          Cp[(size_t)(crow0 + m * 32 + j) * ldc + ccol0 + n * 64] = acc[m][n][j];
  }
}

// ---- scale: attn = E / s, s = sum of 32 col-block partials; also 1/s -------
__global__ void scale_kernel(const unsigned short* __restrict__ E,
                             const float* __restrict__ psum,
                             float* __restrict__ attn, float* __restrict__ sinv) {
  const int row = blockIdx.x, t = threadIdx.x;   // 256 thr
  __shared__ float sh;
  if (t < 64) {
    float p = (t < 32) ? psum[(size_t)t * NB + row] : 0.f;
    #pragma unroll
    for (int o = 16; o > 0; o >>= 1) p += __shfl_xor(p, o);
    if (t == 0) { sh = p; sinv[row] = 1.0f / p; }
  }
  __syncthreads();
  const float inv = 1.0f / sh;
  const unsigned short* erow = E + (size_t)row * NM;
  float* arow = attn + (size_t)row * NM;
  #pragma unroll
  for (int i = 0; i < 4; ++i) {
    u16x8 bv = ((const u16x8*)erow)[i * 256 + t];
    float4 f0, f1;
    #pragma unroll
    for (int j = 0; j < 8; ++j) {
      const float a = bf2f(bv[j]) * inv;
      if (j < 4) (&f0.x)[j] = a; else (&f1.x)[j - 4] = a;
    }
    const int e = (i * 256 + t) * 8;
    *(float4*)(arow + e) = f0;
    *(float4*)(arow + e + 4) = f1;
  }
}

// ---- reduce partials: mf = (sum_k part[k]) * sinv[row], S = 4 --------------
__global__ void reduce_kernel(const float4* __restrict__ part, float4* __restrict__ mf,
                              const float* __restrict__ sinv) {
  const size_t n4 = (size_t)NB * ND / 4;
  for (size_t i = (size_t)blockIdx.x * blockDim.x + threadIdx.x; i < n4;
       i += (size_t)gridDim.x * blockDim.x) {
    const float is = sinv[i >> 8];   // 256 float4 per row
    float4 s = part[i];
    #pragma unroll
    for (int k = 1; k < 4; ++k) {
      float4 p = part[(size_t)k * n4 + i];
      s.x += p.x; s.y += p.y; s.z += p.z; s.w += p.w;
    }
    s.x *= is; s.y *= is; s.z *= is; s.w *= is;
    mf[i] = s;
  }
}

extern "C" void kernel_launch(void* const* d_in, const int* in_sizes, int n_in,
                              void* d_out, int out_size, void* d_ws, size_t ws_size,
                              hipStream_t stream) {
  const float* q   = (const float*)d_in[0];
  const float* mem = (const float*)d_in[1];
  float* mf   = (float*)d_out;                       // [4096 x 1024]
  float* attn = (float*)d_out + (size_t)NB * ND;     // [4096 x 8192]
  char* ws = (char*)d_ws;
  unsigned short* qn   = (unsigned short*)(ws);                        // 8 MiB
  unsigned short* memn = (unsigned short*)(ws + ((size_t)8  << 20));   // 16 MiB
  unsigned short* memt = (unsigned short*)(ws + ((size_t)24 << 20));   // 16 MiB
  unsigned short* E    = (unsigned short*)(ws + ((size_t)40 << 20));   // 64 MiB
  float* psum          = (float*)(ws + ((size_t)104 << 20));           // 512 KiB
  float* sinv          = (float*)(ws + ((size_t)104 << 20) + (512 << 10)); // 16 KiB
  float* part          = (float*)(ws + ((size_t)105 << 20));           // 64 MiB

  hipFuncSetAttribute((const void*)gemm4r<1>,
                      hipFuncAttributeMaxDynamicSharedMemorySize, 131072);
  hipFuncSetAttribute((const void*)gemm4r<0>,
                      hipFuncAttributeMaxDynamicSharedMemorySize, 131072);

  hipLaunchKernelGGL(nrm_kernel, dim3(NM), dim3(256), 0, stream, mem, memn);
  hipLaunchKernelGGL(nrm_kernel, dim3(NB), dim3(256), 0, stream, q, qn);
  hipLaunchKernelGGL(tr_kernel, dim3(ND / 64, NM / 64), dim3(256), 0, stream, memn, memt);

  // E = exp(qn * memn^T) bf16 + psum : M=4096, N=8192, K=1024; 512 tiles.
  hipLaunchKernelGGL((gemm4r<1>), dim3((NB / 256) * (NM / 256)), dim3(512), 131072, stream,
                     qn, memn, (void*)E, psum, ND, NM, NB / 256,
                     (NB / 256) * (NM / 256), ND, 0ULL);

  // attn = E / s (fp32 out) + sinv
  hipLaunchKernelGGL(scale_kernel, dim3(NB), dim3(256), 0, stream, E, psum, attn, sinv);

  // part[k] = E * memt^T (k-slice) : M=4096, N=1024, K=8192, S=4 (kchunk 2048)
  const int tps = (NB / 256) * (ND / 256);   // 64
  hipLaunchKernelGGL((gemm4r<0>), dim3(tps * 4), dim3(512), 131072, stream,
                     E, memt, (void*)part, (float*)nullptr, NM, ND, NB / 256, tps, NM / 4,
                     (unsigned long long)NB * ND);
  hipLaunchKernelGGL(reduce_kernel, dim3(2048), dim3(256), 0, stream,
                     (const float4*)part, (float4*)mf, sinv);
}